// Round 5
// baseline (159.036 us; speedup 1.0000x reference)
//
#include <hip/hip_runtime.h>
#include <hip/hip_bf16.h>
#include <math.h>

// Problem constants
#define Bsz  4
#define Lseq 4096
#define Dd   1024
#define Ss   64
#define RTOT (Bsz*Lseq)        // 16384 rows total

// Scan chunking: ||A||_op ~ 0.16 => ||A^12|| <= 3e-10, warm-up start exact to fp32
#define LC   16
#define WARM 12
#define CHUNKS_PER_B (Lseq/LC) // 256

typedef __attribute__((ext_vector_type(8))) short short8;
typedef __attribute__((ext_vector_type(4))) float f32x4;

__device__ __forceinline__ ushort f2bf(float f) {
  unsigned u = __float_as_uint(f);
  unsigned r = (u + 0x7FFFu + ((u >> 16) & 1u)) >> 16;   // RNE
  return (ushort)r;
}

// v_cvt_pk_bf16_f32 path (compiler-scheduled, RNE)
__device__ __forceinline__ unsigned cvtpk(float lo, float hi) {
  __hip_bfloat162 h = __float22bfloat162_rn(make_float2(lo, hi));
  union { __hip_bfloat162 h; unsigned u; } c; c.h = h;
  return c.u;
}

__device__ __forceinline__ short8 pack8v(f32x4 a, f32x4 b) {
  union { short8 s; unsigned u[4]; } r;
  r.u[0] = cvtpk(a[0], a[1]);
  r.u[1] = cvtpk(a[2], a[3]);
  r.u[2] = cvtpk(b[0], b[1]);
  r.u[3] = cvtpk(b[2], b[3]);
  return r.s;
}

// ---------------- prep: Bm, C -> bf16 ----------------
__global__ __launch_bounds__(256) void k_prep(const float* __restrict__ Bm,
                                              const float* __restrict__ C,
                                              ushort* __restrict__ Bmb,
                                              ushort* __restrict__ Cb) {
  int idx = blockIdx.x * 256 + threadIdx.x;   // float4 index, 32768 total
  const float* src; ushort* dst; int off;
  if (idx < 16384) { src = Bm; dst = Bmb; off = idx; }
  else             { src = C;  dst = Cb;  off = idx - 16384; }
  float4 v = *(const float4*)&src[(size_t)off*4];
  ushort4 o;
  o.x = f2bf(v.x); o.y = f2bf(v.y); o.z = f2bf(v.z); o.w = f2bf(v.w);
  *(ushort4*)&dst[(size_t)off*4] = o;
}

// ---------------- GEMM1 (MFMA, LDS-free): uB[r][n] = sum_k x[r][k]*Bm[n][k] ----
// Block 256 = 4 waves = 2m x 2n. Wave: 16 rows x 32 cols, K=1024.
// A-frag: lane l holds x[row0 + (l&15)][k0 + 8*(l>>4) + i]  (32B contiguous/lane)
// D: col = lane&15, row = 4*(lane>>4) + reg   (m89-verified)
__global__ __launch_bounds__(256) void k_gemm1(const float* __restrict__ x,
                                               const ushort* __restrict__ Bmb,
                                               float* __restrict__ uB) {
  const int l  = threadIdx.x & 63;
  const int wv = threadIdx.x >> 6;
  const int wm = wv >> 1, wn = wv & 1;
  const int row0 = blockIdx.x * 32 + wm * 16;
  const int n0   = wn * 32;
  const int lr = l & 15, lq = l >> 4;

  f32x4 acc0 = {0.f,0.f,0.f,0.f}, acc1 = {0.f,0.f,0.f,0.f};
  const f32x4*  xa  = (const f32x4*)(x + (size_t)(row0 + lr) * Dd + 8*lq);
  const ushort* bp0 = Bmb + (size_t)(n0      + lr) * Dd + 8*lq;
  const ushort* bp1 = Bmb + (size_t)(n0 + 16 + lr) * Dd + 8*lq;

  #pragma unroll 8
  for (int ks = 0; ks < 32; ++ks) {
    f32x4 alo = __builtin_nontemporal_load(xa + 8*ks);
    f32x4 ahi = __builtin_nontemporal_load(xa + 8*ks + 1);
    short8 b0 = *(const short8*)(bp0 + 32*ks);
    short8 b1 = *(const short8*)(bp1 + 32*ks);
    short8 a  = pack8v(alo, ahi);
    acc0 = __builtin_amdgcn_mfma_f32_16x16x32_bf16(a, b0, acc0, 0, 0, 0);
    acc1 = __builtin_amdgcn_mfma_f32_16x16x32_bf16(a, b1, acc1, 0, 0, 0);
  }
  const int orow = row0 + 4*lq;
  #pragma unroll
  for (int j = 0; j < 4; ++j) {
    uB[(size_t)(orow + j)*Ss + n0 + lr]      = acc0[j];
    uB[(size_t)(orow + j)*Ss + n0 + 16 + lr] = acc1[j];
  }
}

// ---------------- Scan: s_t = A s_{t-1} + u_t (chunked, warm-up), bf16 out ----
__device__ __forceinline__ float bcast_lane(float v, int l) {
  return __int_as_float(__builtin_amdgcn_readlane(__float_as_int(v), l));
}

__global__ __launch_bounds__(256) void k_scan(const float* __restrict__ uB,
                                              const float* __restrict__ A,
                                              ushort* __restrict__ stb) {
  const int lane  = threadIdx.x & 63;
  const int wv    = threadIdx.x >> 6;
  const int chunk = blockIdx.x * 4 + wv;        // 0..1023
  const int b     = chunk >> 8;
  const int c     = chunk & (CHUNKS_PER_B-1);

  float arow[64];
  #pragma unroll
  for (int i = 0; i < 64; i += 4) {
    float4 v = *(const float4*)&A[lane*64 + i];
    arow[i] = v.x; arow[i+1] = v.y; arow[i+2] = v.z; arow[i+3] = v.w;
  }

  const int cs = c * LC;
  const int t0 = (cs >= WARM) ? (cs - WARM) : 0;
  float s = 0.f;
  const float* up = uB  + ((size_t)b*Lseq + t0)*Ss + lane;
  ushort*      sp = stb + ((size_t)b*Lseq + cs)*Ss + lane;

  for (int tt = t0; tt < cs + LC; ++tt, up += Ss) {
    float u = *up;
    float a0 = u, a1 = 0.f, a2 = 0.f, a3 = 0.f;
    #pragma unroll
    for (int i = 0; i < 64; i += 4) {
      a0 += bcast_lane(s, i  ) * arow[i  ];
      a1 += bcast_lane(s, i+1) * arow[i+1];
      a2 += bcast_lane(s, i+2) * arow[i+2];
      a3 += bcast_lane(s, i+3) * arow[i+3];
    }
    s = (a0 + a1) + (a2 + a3);
    if (tt >= cs) { *sp = f2bf(s); sp += Ss; }
  }
}

// ---------------- Fused out (MFMA): y = st@C.T, GELU(erf), LayerNorm, clamp ----
// 32 rows/block (2 m-tiles), 4 waves each owning a 256-col d-quadrant.
// ALL loops touching acc are FULLY unrolled (rule #20: partial unroll ->
// runtime index -> acc spills to scratch; this was the r2-r4 260MB "write").
__device__ __forceinline__ float fixv(float v) {
  if (isnan(v)) return 0.f;
  if (isinf(v)) return v > 0.f ? 1000000.0f : -1000000.0f;
  return v;
}

__global__ __launch_bounds__(256, 2) void k_out(const ushort* __restrict__ stb,
                                                const ushort* __restrict__ Cb,
                                                const float* __restrict__ gamma,
                                                const float* __restrict__ beta,
                                                float* __restrict__ out) {
  __shared__ float red[4][4][2][4][2];            // [wv][lq][m][j][sum/sq]
  __shared__ float mrs[32][2];
  __shared__ __align__(16) float ol[16][516];     // 33 KB staging for coalesced out
  const int t  = threadIdx.x;
  const int l  = t & 63;
  const int wv = t >> 6;
  const int lr = l & 15, lq = l >> 4;
  const size_t row0 = (size_t)blockIdx.x * 32;

  // A-frags straight from global: lane l -> st[row0 + 16m + lr][8*lq + i (+32)]
  short8 aA[2][2];
  #pragma unroll
  for (int m = 0; m < 2; ++m) {
    const ushort* ap = stb + (row0 + m*16 + lr)*Ss + 8*lq;
    aA[m][0] = *(const short8*)(ap);
    aA[m][1] = *(const short8*)(ap + 32);
  }

  const int d0 = wv * 256;
  f32x4 acc[2][16];
  #pragma unroll
  for (int m = 0; m < 2; ++m)
    #pragma unroll
    for (int tt = 0; tt < 16; ++tt) acc[m][tt] = (f32x4){0.f,0.f,0.f,0.f};

  const ushort* cbase = Cb + (size_t)(d0 + lr)*Ss + 8*lq;
  #pragma unroll
  for (int tt = 0; tt < 16; ++tt) {
    const ushort* cp = cbase + (size_t)tt*16*Ss;
    short8 b0 = *(const short8*)(cp);
    short8 b1 = *(const short8*)(cp + 32);
    acc[0][tt] = __builtin_amdgcn_mfma_f32_16x16x32_bf16(aA[0][0], b0, acc[0][tt], 0, 0, 0);
    acc[0][tt] = __builtin_amdgcn_mfma_f32_16x16x32_bf16(aA[0][1], b1, acc[0][tt], 0, 0, 0);
    acc[1][tt] = __builtin_amdgcn_mfma_f32_16x16x32_bf16(aA[1][0], b0, acc[1][tt], 0, 0, 0);
    acc[1][tt] = __builtin_amdgcn_mfma_f32_16x16x32_bf16(aA[1][1], b1, acc[1][tt], 0, 0, 0);
  }

  // GELU (exact erf) + per-row partials. acc[m][tt][j] at (row 16m+4lq+j, d d0+16tt+lr)
  float ps[2][4], pq[2][4];
  #pragma unroll
  for (int m = 0; m < 2; ++m)
    #pragma unroll
    for (int j = 0; j < 4; ++j) { ps[m][j] = 0.f; pq[m][j] = 0.f; }
  #pragma unroll
  for (int m = 0; m < 2; ++m)
    #pragma unroll
    for (int tt = 0; tt < 16; ++tt)
      #pragma unroll
      for (int j = 0; j < 4; ++j) {
        float v = acc[m][tt][j];
        float g = 0.5f * v * (1.f + erff(v * 0.70710678118654752f));
        acc[m][tt][j] = g;
        ps[m][j] += g;
        pq[m][j] += g * g;
      }
  // butterfly across the 16-lane group
  #pragma unroll
  for (int off = 1; off < 16; off <<= 1)
    #pragma unroll
    for (int m = 0; m < 2; ++m)
      #pragma unroll
      for (int j = 0; j < 4; ++j) {
        ps[m][j] += __shfl_xor(ps[m][j], off);
        pq[m][j] += __shfl_xor(pq[m][j], off);
      }
  if (lr == 0) {
    #pragma unroll
    for (int m = 0; m < 2; ++m)
      #pragma unroll
      for (int j = 0; j < 4; ++j) {
        red[wv][lq][m][j][0] = ps[m][j];
        red[wv][lq][m][j][1] = pq[m][j];
      }
  }
  __syncthreads();
  if (t < 32) {
    const int m = t >> 4, g = (t >> 2) & 3, j = t & 3;  // row = t
    float sm = red[0][g][m][j][0] + red[1][g][m][j][0] + red[2][g][m][j][0] + red[3][g][m][j][0];
    float sq = red[0][g][m][j][1] + red[1][g][m][j][1] + red[2][g][m][j][1] + red[3][g][m][j][1];
    float mean = sm * (1.f/1024.f);
    float var  = sq * (1.f/1024.f) - mean*mean;
    mrs[t][0] = mean;
    mrs[t][1] = rsqrtf(var + 1e-5f);
  }
  __syncthreads();

  // Epilogue: 4 passes (m-half x d-half): normalize -> LDS -> NT coalesced writes
  #pragma unroll
  for (int pp = 0; pp < 4; ++pp) {
    const int m  = pp >> 1;
    const int ph = pp & 1;
    if ((wv >> 1) == ph) {
      #pragma unroll
      for (int tt = 0; tt < 16; ++tt) {
        const int d  = d0 + 16*tt + lr;
        const int dl = (wv & 1)*256 + 16*tt + lr;
        const float gm = gamma[d], be = beta[d];
        #pragma unroll
        for (int j = 0; j < 4; ++j) {
          const int r = 4*lq + j;                 // local row 0..15
          const int rowm = 16*m + r;
          float o = (acc[m][tt][j] - mrs[rowm][0]) * mrs[rowm][1] * gm + be;
          ol[r][dl] = fixv(o);
        }
      }
    }
    __syncthreads();
    #pragma unroll
    for (int it = 0; it < 8; ++it) {
      const int flat = it*256 + t;     // float4 id in [16][128]
      const int r  = flat >> 7;
      const int c4 = flat & 127;
      f32x4 v = *(const f32x4*)&ol[r][c4*4];
      __builtin_nontemporal_store(v, (f32x4*)&out[(row0 + 16*m + r)*Dd + ph*512 + c4*4]);
    }
    __syncthreads();
  }
}

extern "C" void kernel_launch(void* const* d_in, const int* in_sizes, int n_in,
                              void* d_out, int out_size, void* d_ws, size_t ws_size,
                              hipStream_t stream) {
  (void)in_sizes; (void)n_in; (void)out_size; (void)ws_size;
  const float* x     = (const float*)d_in[0];
  const float* A     = (const float*)d_in[1];
  const float* Bm    = (const float*)d_in[2];
  const float* C     = (const float*)d_in[3];
  const float* gamma = (const float*)d_in[4];
  const float* beta  = (const float*)d_in[5];
  float* out = (float*)d_out;

  // ws: uB f32 (4 MB) | states bf16 (2 MB) | C bf16 (128 KB) | Bm bf16 (128 KB)
  float*  uB  = (float*)d_ws;
  ushort* stb = (ushort*)(uB + (size_t)RTOT * Ss);
  ushort* Cb  = stb + (size_t)RTOT * Ss;
  ushort* Bmb = Cb + (size_t)Dd * Ss;

  k_prep <<<128, 256, 0, stream>>>(Bm, C, Bmb, Cb);
  k_gemm1<<<RTOT/32, 256, 0, stream>>>(x, Bmb, uB);
  k_scan <<<(Bsz*CHUNKS_PER_B)/4, 256, 0, stream>>>(uB, A, stb);
  k_out  <<<RTOT/32, 256, 0, stream>>>(stb, Cb, gamma, beta, out);
}

// Round 6
// 112.086 us; speedup vs baseline: 1.4189x; 1.4189x over previous
//
#include <hip/hip_runtime.h>
#include <hip/hip_bf16.h>
#include <math.h>

// Problem constants
#define Bsz  4
#define Lseq 4096
#define Dd   1024
#define Ss   64
#define RTOT (Bsz*Lseq)        // 16384 rows total

// Scan chunking: ||A||_op ~ 0.16 => ||A^12|| <= 3e-10, warm-up start exact to fp32
#define LC   16
#define WARM 12
#define CHUNKS_PER_B (Lseq/LC) // 256

typedef __attribute__((ext_vector_type(8))) short short8;
typedef __attribute__((ext_vector_type(4))) float f32x4;

__device__ __forceinline__ ushort f2bf(float f) {
  unsigned u = __float_as_uint(f);
  unsigned r = (u + 0x7FFFu + ((u >> 16) & 1u)) >> 16;   // RNE
  return (ushort)r;
}

// v_cvt_pk_bf16_f32 path (compiler-scheduled, RNE)
__device__ __forceinline__ unsigned cvtpk(float lo, float hi) {
  __hip_bfloat162 h = __float22bfloat162_rn(make_float2(lo, hi));
  union { __hip_bfloat162 h; unsigned u; } c; c.h = h;
  return c.u;
}

__device__ __forceinline__ short8 pack8v(f32x4 a, f32x4 b) {
  union { short8 s; unsigned u[4]; } r;
  r.u[0] = cvtpk(a[0], a[1]);
  r.u[1] = cvtpk(a[2], a[3]);
  r.u[2] = cvtpk(b[0], b[1]);
  r.u[3] = cvtpk(b[2], b[3]);
  return r.s;
}

// Inline exact-erf GELU (A&S 7.1.26, |eps|<=1.5e-7) — NO library call, so the
// accumulator array never crosses a call boundary (r5's spill suspect #1).
__device__ __forceinline__ float gelu_erf(float v) {
  float x  = v * 0.70710678118654752f;
  float ax = fabsf(x);
  float t  = __builtin_amdgcn_rcpf(fmaf(0.3275911f, ax, 1.f));
  float p  = fmaf(1.061405429f, t, -1.453152027f);
  p = fmaf(p, t, 1.421413741f);
  p = fmaf(p, t, -0.284496736f);
  p = fmaf(p, t, 0.254829592f);
  p = p * t;
  float e  = __expf(-x * x);
  float er = fmaf(-p, e, 1.f);          // erf(|x|)
  er = copysignf(er, x);
  return 0.5f * v * (1.f + er);
}

// ---------------- prep: Bm, C -> bf16 ----------------
__global__ __launch_bounds__(256) void k_prep(const float* __restrict__ Bm,
                                              const float* __restrict__ C,
                                              ushort* __restrict__ Bmb,
                                              ushort* __restrict__ Cb) {
  int idx = blockIdx.x * 256 + threadIdx.x;   // float4 index, 32768 total
  const float* src; ushort* dst; int off;
  if (idx < 16384) { src = Bm; dst = Bmb; off = idx; }
  else             { src = C;  dst = Cb;  off = idx - 16384; }
  float4 v = *(const float4*)&src[(size_t)off*4];
  ushort4 o;
  o.x = f2bf(v.x); o.y = f2bf(v.y); o.z = f2bf(v.z); o.w = f2bf(v.w);
  *(ushort4*)&dst[(size_t)off*4] = o;
}

// ---------------- GEMM1 (MFMA, LDS-free): uB[r][n] = sum_k x[r][k]*Bm[n][k] ----
// Block 256 = 4 waves = 2m x 2n. Wave: 16 rows x 32 cols, K=1024.
// A-frag: lane l holds x[row0 + (l&15)][k0 + 8*(l>>4) + i]  (32B contiguous/lane)
// D: col = lane&15, row = 4*(lane>>4) + reg   (m89-verified)
__global__ __launch_bounds__(256) void k_gemm1(const float* __restrict__ x,
                                               const ushort* __restrict__ Bmb,
                                               float* __restrict__ uB) {
  const int l  = threadIdx.x & 63;
  const int wv = threadIdx.x >> 6;
  const int wm = wv >> 1, wn = wv & 1;
  const int row0 = blockIdx.x * 32 + wm * 16;
  const int n0   = wn * 32;
  const int lr = l & 15, lq = l >> 4;

  f32x4 acc0 = {0.f,0.f,0.f,0.f}, acc1 = {0.f,0.f,0.f,0.f};
  const f32x4*  xa  = (const f32x4*)(x + (size_t)(row0 + lr) * Dd + 8*lq);
  const ushort* bp0 = Bmb + (size_t)(n0      + lr) * Dd + 8*lq;
  const ushort* bp1 = Bmb + (size_t)(n0 + 16 + lr) * Dd + 8*lq;

  #pragma unroll 8
  for (int ks = 0; ks < 32; ++ks) {
    f32x4 alo = __builtin_nontemporal_load(xa + 8*ks);
    f32x4 ahi = __builtin_nontemporal_load(xa + 8*ks + 1);
    short8 b0 = *(const short8*)(bp0 + 32*ks);
    short8 b1 = *(const short8*)(bp1 + 32*ks);
    short8 a  = pack8v(alo, ahi);
    acc0 = __builtin_amdgcn_mfma_f32_16x16x32_bf16(a, b0, acc0, 0, 0, 0);
    acc1 = __builtin_amdgcn_mfma_f32_16x16x32_bf16(a, b1, acc1, 0, 0, 0);
  }
  const int orow = row0 + 4*lq;
  #pragma unroll
  for (int j = 0; j < 4; ++j) {
    uB[(size_t)(orow + j)*Ss + n0 + lr]      = acc0[j];
    uB[(size_t)(orow + j)*Ss + n0 + 16 + lr] = acc1[j];
  }
}

// ---------------- Scan: s_t = A s_{t-1} + u_t (chunked, warm-up), bf16 out ----
__device__ __forceinline__ float bcast_lane(float v, int l) {
  return __int_as_float(__builtin_amdgcn_readlane(__float_as_int(v), l));
}

__global__ __launch_bounds__(256) void k_scan(const float* __restrict__ uB,
                                              const float* __restrict__ A,
                                              ushort* __restrict__ stb) {
  const int lane  = threadIdx.x & 63;
  const int wv    = threadIdx.x >> 6;
  const int chunk = blockIdx.x * 4 + wv;        // 0..1023
  const int b     = chunk >> 8;
  const int c     = chunk & (CHUNKS_PER_B-1);

  float arow[64];
  #pragma unroll
  for (int i = 0; i < 64; i += 4) {
    float4 v = *(const float4*)&A[lane*64 + i];
    arow[i] = v.x; arow[i+1] = v.y; arow[i+2] = v.z; arow[i+3] = v.w;
  }

  const int cs = c * LC;
  const int t0 = (cs >= WARM) ? (cs - WARM) : 0;
  float s = 0.f;
  const float* up = uB  + ((size_t)b*Lseq + t0)*Ss + lane;
  ushort*      sp = stb + ((size_t)b*Lseq + cs)*Ss + lane;

  for (int tt = t0; tt < cs + LC; ++tt, up += Ss) {
    float u = *up;
    float a0 = u, a1 = 0.f, a2 = 0.f, a3 = 0.f;
    #pragma unroll
    for (int i = 0; i < 64; i += 4) {
      a0 += bcast_lane(s, i  ) * arow[i  ];
      a1 += bcast_lane(s, i+1) * arow[i+1];
      a2 += bcast_lane(s, i+2) * arow[i+2];
      a3 += bcast_lane(s, i+3) * arow[i+3];
    }
    s = (a0 + a1) + (a2 + a3);
    if (tt >= cs) { *sp = f2bf(s); sp += Ss; }
  }
}

// ---------------- Fused out (MFMA): y = st@C.T, GELU(erf), LayerNorm, clamp ----
// 16 rows/block, 4 waves each owning a 256-col d-quadrant. acc = 64 floats ->
// fits registers even at a 128-VGPR budget. All acc loops fully unrolled.
__device__ __forceinline__ float fixv(float v) {
  if (isnan(v)) return 0.f;
  if (isinf(v)) return v > 0.f ? 1000000.0f : -1000000.0f;
  return v;
}

__global__ __launch_bounds__(256) void k_out(const ushort* __restrict__ stb,
                                             const ushort* __restrict__ Cb,
                                             const float* __restrict__ gamma,
                                             const float* __restrict__ beta,
                                             float* __restrict__ out) {
  __shared__ __align__(16) ushort stl[16*64];     // 2 KB
  __shared__ float red[4][4][4][2];
  __shared__ float mrs[16][2];
  __shared__ __align__(16) float ol[16][516];     // 33 KB staging for coalesced out
  const int t  = threadIdx.x;
  const int l  = t & 63;
  const int wv = t >> 6;
  const int lr = l & 15, lq = l >> 4;
  const size_t row0 = (size_t)blockIdx.x * 16;

  *(ushort4*)&stl[t*4] = *(const ushort4*)&stb[row0*Ss + t*4];
  __syncthreads();

  // A-frags: lane l -> st[lr][8*lq + i (+32)]
  short8 a0 = *(const short8*)&stl[lr*64 + 8*lq];
  short8 a1 = *(const short8*)&stl[lr*64 + 8*lq + 32];

  const int d0 = wv * 256;
  f32x4 acc[16];
  #pragma unroll
  for (int tt = 0; tt < 16; ++tt) acc[tt] = (f32x4){0.f,0.f,0.f,0.f};

  const ushort* cbase = Cb + (size_t)(d0 + lr)*Ss + 8*lq;
  #pragma unroll
  for (int tt = 0; tt < 16; ++tt) {
    const ushort* cp = cbase + (size_t)tt*16*Ss;
    short8 b0 = *(const short8*)(cp);
    short8 b1 = *(const short8*)(cp + 32);
    acc[tt] = __builtin_amdgcn_mfma_f32_16x16x32_bf16(a0, b0, acc[tt], 0, 0, 0);
    acc[tt] = __builtin_amdgcn_mfma_f32_16x16x32_bf16(a1, b1, acc[tt], 0, 0, 0);
  }

  // GELU (inline exact erf) + per-row partials. acc[tt][j] at (row 4*lq+j, d d0+16*tt+lr)
  float ps[4] = {0,0,0,0}, pq[4] = {0,0,0,0};
  #pragma unroll
  for (int tt = 0; tt < 16; ++tt) {
    #pragma unroll
    for (int j = 0; j < 4; ++j) {
      float g = gelu_erf(acc[tt][j]);
      acc[tt][j] = g;
      ps[j] += g;
      pq[j] += g * g;
    }
  }
  // butterfly across the 16-lane group (sums over this wave's d-quadrant)
  #pragma unroll
  for (int off = 1; off < 16; off <<= 1) {
    #pragma unroll
    for (int j = 0; j < 4; ++j) {
      ps[j] += __shfl_xor(ps[j], off);
      pq[j] += __shfl_xor(pq[j], off);
    }
  }
  if (lr == 0) {
    #pragma unroll
    for (int j = 0; j < 4; ++j) {
      red[wv][lq][j][0] = ps[j];
      red[wv][lq][j][1] = pq[j];
    }
  }
  __syncthreads();
  if (t < 16) {
    const int g = t >> 2, j = t & 3;    // row t = 4g + j
    float sm = red[0][g][j][0] + red[1][g][j][0] + red[2][g][j][0] + red[3][g][j][0];
    float sq = red[0][g][j][1] + red[1][g][j][1] + red[2][g][j][1] + red[3][g][j][1];
    float mean = sm * (1.f/1024.f);
    float var  = sq * (1.f/1024.f) - mean*mean;
    mrs[t][0] = mean;
    mrs[t][1] = rsqrtf(var + 1e-5f);
  }
  __syncthreads();

  // Epilogue: normalize -> LDS stage (half the d-range at a time) -> NT coalesced writes
  #pragma unroll
  for (int p = 0; p < 2; ++p) {
    if ((wv >> 1) == p) {
      #pragma unroll
      for (int tt = 0; tt < 16; ++tt) {
        const int d  = d0 + 16*tt + lr;
        const int dl = (wv & 1)*256 + 16*tt + lr;
        const float gm = gamma[d], be = beta[d];
        #pragma unroll
        for (int j = 0; j < 4; ++j) {
          const int r = 4*lq + j;
          float o = (acc[tt][j] - mrs[r][0]) * mrs[r][1] * gm + be;
          ol[r][dl] = fixv(o);
        }
      }
    }
    __syncthreads();
    #pragma unroll
    for (int it = 0; it < 8; ++it) {
      const int flat = it*256 + t;     // float4 id in [16][128]
      const int r  = flat >> 7;
      const int c4 = flat & 127;
      f32x4 v = *(const f32x4*)&ol[r][c4*4];
      __builtin_nontemporal_store(v, (f32x4*)&out[(row0 + r)*Dd + p*512 + c4*4]);
    }
    __syncthreads();
  }
}

extern "C" void kernel_launch(void* const* d_in, const int* in_sizes, int n_in,
                              void* d_out, int out_size, void* d_ws, size_t ws_size,
                              hipStream_t stream) {
  (void)in_sizes; (void)n_in; (void)out_size; (void)ws_size;
  const float* x     = (const float*)d_in[0];
  const float* A     = (const float*)d_in[1];
  const float* Bm    = (const float*)d_in[2];
  const float* C     = (const float*)d_in[3];
  const float* gamma = (const float*)d_in[4];
  const float* beta  = (const float*)d_in[5];
  float* out = (float*)d_out;

  // ws: uB f32 (4 MB) | states bf16 (2 MB) | C bf16 (128 KB) | Bm bf16 (128 KB)
  float*  uB  = (float*)d_ws;
  ushort* stb = (ushort*)(uB + (size_t)RTOT * Ss);
  ushort* Cb  = stb + (size_t)RTOT * Ss;
  ushort* Bmb = Cb + (size_t)Dd * Ss;

  k_prep <<<128, 256, 0, stream>>>(Bm, C, Bmb, Cb);
  k_gemm1<<<RTOT/32, 256, 0, stream>>>(x, Bmb, uB);
  k_scan <<<(Bsz*CHUNKS_PER_B)/4, 256, 0, stream>>>(uB, A, stb);
  k_out  <<<RTOT/16, 256, 0, stream>>>(stb, Cb, gamma, beta, out);
}

// Round 7
// 91.901 us; speedup vs baseline: 1.7305x; 1.2196x over previous
//
#include <hip/hip_runtime.h>
#include <hip/hip_bf16.h>
#include <math.h>

// Problem constants
#define Bsz  4
#define Lseq 4096
#define Dd   1024
#define Ss   64
#define RTOT (Bsz*Lseq)        // 16384 rows total

// Scan chunking: ||A||_op ~ 0.16 => ||A^12|| <= 3e-10, warm-up start exact to fp32
#define LC   16
#define WARM 12
#define CHUNKS_PER_B (Lseq/LC) // 256

typedef __attribute__((ext_vector_type(8))) short short8;
typedef __attribute__((ext_vector_type(4))) float f32x4;

__device__ __forceinline__ ushort f2bf(float f) {
  unsigned u = __float_as_uint(f);
  unsigned r = (u + 0x7FFFu + ((u >> 16) & 1u)) >> 16;   // RNE
  return (ushort)r;
}

// v_cvt_pk_bf16_f32 path (compiler-scheduled, RNE)
__device__ __forceinline__ unsigned cvtpk(float lo, float hi) {
  __hip_bfloat162 h = __float22bfloat162_rn(make_float2(lo, hi));
  union { __hip_bfloat162 h; unsigned u; } c; c.h = h;
  return c.u;
}

__device__ __forceinline__ short8 pack8v(f32x4 a, f32x4 b) {
  union { short8 s; unsigned u[4]; } r;
  r.u[0] = cvtpk(a[0], a[1]);
  r.u[1] = cvtpk(a[2], a[3]);
  r.u[2] = cvtpk(b[0], b[1]);
  r.u[3] = cvtpk(b[2], b[3]);
  return r.s;
}

// Inline exact-erf GELU (A&S 7.1.26, |eps|<=1.5e-7) — no call boundary.
__device__ __forceinline__ float gelu_erf(float v) {
  float x  = v * 0.70710678118654752f;
  float ax = fabsf(x);
  float t  = __builtin_amdgcn_rcpf(fmaf(0.3275911f, ax, 1.f));
  float p  = fmaf(1.061405429f, t, -1.453152027f);
  p = fmaf(p, t, 1.421413741f);
  p = fmaf(p, t, -0.284496736f);
  p = fmaf(p, t, 0.254829592f);
  p = p * t;
  float e  = __expf(-x * x);
  float er = fmaf(-p, e, 1.f);          // erf(|x|)
  er = copysignf(er, x);
  return 0.5f * v * (1.f + er);
}

// ---------------- prep: Bm, C -> bf16 ----------------
__global__ __launch_bounds__(256) void k_prep(const float* __restrict__ Bm,
                                              const float* __restrict__ C,
                                              ushort* __restrict__ Bmb,
                                              ushort* __restrict__ Cb) {
  int idx = blockIdx.x * 256 + threadIdx.x;   // float4 index, 32768 total
  const float* src; ushort* dst; int off;
  if (idx < 16384) { src = Bm; dst = Bmb; off = idx; }
  else             { src = C;  dst = Cb;  off = idx - 16384; }
  float4 v = *(const float4*)&src[(size_t)off*4];
  ushort4 o;
  o.x = f2bf(v.x); o.y = f2bf(v.y); o.z = f2bf(v.z); o.w = f2bf(v.w);
  *(ushort4*)&dst[(size_t)off*4] = o;
}

// ---------------- GEMM1 (MFMA, LDS-free): uB[r][n] = sum_k x[r][k]*Bm[n][k] ----
// Block 256 = 4 waves = 2m x 2n. Wave: 16 rows x 32 cols, K=1024.
// Plain (cached) x loads: the 2 waves sharing rows hit L2 on the second read.
__global__ __launch_bounds__(256) void k_gemm1(const float* __restrict__ x,
                                               const ushort* __restrict__ Bmb,
                                               float* __restrict__ uB) {
  const int l  = threadIdx.x & 63;
  const int wv = threadIdx.x >> 6;
  const int wm = wv >> 1, wn = wv & 1;
  const int row0 = blockIdx.x * 32 + wm * 16;
  const int n0   = wn * 32;
  const int lr = l & 15, lq = l >> 4;

  f32x4 acc0 = {0.f,0.f,0.f,0.f}, acc1 = {0.f,0.f,0.f,0.f};
  const f32x4*  xa  = (const f32x4*)(x + (size_t)(row0 + lr) * Dd + 8*lq);
  const ushort* bp0 = Bmb + (size_t)(n0      + lr) * Dd + 8*lq;
  const ushort* bp1 = Bmb + (size_t)(n0 + 16 + lr) * Dd + 8*lq;

  #pragma unroll 8
  for (int ks = 0; ks < 32; ++ks) {
    f32x4 alo = xa[8*ks];
    f32x4 ahi = xa[8*ks + 1];
    short8 b0 = *(const short8*)(bp0 + 32*ks);
    short8 b1 = *(const short8*)(bp1 + 32*ks);
    short8 a  = pack8v(alo, ahi);
    acc0 = __builtin_amdgcn_mfma_f32_16x16x32_bf16(a, b0, acc0, 0, 0, 0);
    acc1 = __builtin_amdgcn_mfma_f32_16x16x32_bf16(a, b1, acc1, 0, 0, 0);
  }
  const int orow = row0 + 4*lq;
  #pragma unroll
  for (int j = 0; j < 4; ++j) {
    uB[(size_t)(orow + j)*Ss + n0 + lr]      = acc0[j];
    uB[(size_t)(orow + j)*Ss + n0 + 16 + lr] = acc1[j];
  }
}

// ---------------- Scan: s_t = A s_{t-1} + u_t (chunked, warm-up), bf16 out ----
__device__ __forceinline__ float bcast_lane(float v, int l) {
  return __int_as_float(__builtin_amdgcn_readlane(__float_as_int(v), l));
}

__global__ __launch_bounds__(256) void k_scan(const float* __restrict__ uB,
                                              const float* __restrict__ A,
                                              ushort* __restrict__ stb) {
  const int lane  = threadIdx.x & 63;
  const int wv    = threadIdx.x >> 6;
  const int chunk = blockIdx.x * 4 + wv;        // 0..1023
  const int b     = chunk >> 8;
  const int c     = chunk & (CHUNKS_PER_B-1);

  float arow[64];
  #pragma unroll
  for (int i = 0; i < 64; i += 4) {
    float4 v = *(const float4*)&A[lane*64 + i];
    arow[i] = v.x; arow[i+1] = v.y; arow[i+2] = v.z; arow[i+3] = v.w;
  }

  const int cs = c * LC;
  const int t0 = (cs >= WARM) ? (cs - WARM) : 0;
  float s = 0.f;
  const float* up = uB  + ((size_t)b*Lseq + t0)*Ss + lane;
  ushort*      sp = stb + ((size_t)b*Lseq + cs)*Ss + lane;

  for (int tt = t0; tt < cs + LC; ++tt, up += Ss) {
    float u = *up;
    float a0 = u, a1 = 0.f, a2 = 0.f, a3 = 0.f;
    #pragma unroll
    for (int i = 0; i < 64; i += 4) {
      a0 += bcast_lane(s, i  ) * arow[i  ];
      a1 += bcast_lane(s, i+1) * arow[i+1];
      a2 += bcast_lane(s, i+2) * arow[i+2];
      a3 += bcast_lane(s, i+3) * arow[i+3];
    }
    s = (a0 + a1) + (a2 + a3);
    if (tt >= cs) { *sp = f2bf(s); sp += Ss; }
  }
}

// ---------------- Fused out (MFMA): y = st@C.T, GELU(erf), LayerNorm, clamp ----
// 16 rows/block, 4 waves each owning a 256-col d-quadrant.
// Epilogue stores DIRECTLY from acc (no LDS stage, no extra barriers): each
// quarter-wave writes a 64B contiguous segment; L2 merges consecutive-tt
// segments into full lines (r2's "amplification" was spill, not scatter).
__device__ __forceinline__ float fixv(float v) {
  if (isnan(v)) return 0.f;
  if (isinf(v)) return v > 0.f ? 1000000.0f : -1000000.0f;
  return v;
}

__global__ __launch_bounds__(256) void k_out(const ushort* __restrict__ stb,
                                             const ushort* __restrict__ Cb,
                                             const float* __restrict__ gamma,
                                             const float* __restrict__ beta,
                                             float* __restrict__ out) {
  __shared__ __align__(16) ushort stl[16*64];     // 2 KB
  __shared__ float red[4][4][4][2];
  __shared__ float mrs[16][2];
  const int t  = threadIdx.x;
  const int l  = t & 63;
  const int wv = t >> 6;
  const int lr = l & 15, lq = l >> 4;
  const size_t row0 = (size_t)blockIdx.x * 16;

  *(ushort4*)&stl[t*4] = *(const ushort4*)&stb[row0*Ss + t*4];
  __syncthreads();

  // A-frags: lane l -> st[lr][8*lq + i (+32)]
  short8 a0 = *(const short8*)&stl[lr*64 + 8*lq];
  short8 a1 = *(const short8*)&stl[lr*64 + 8*lq + 32];

  const int d0 = wv * 256;
  f32x4 acc[16];
  #pragma unroll
  for (int tt = 0; tt < 16; ++tt) acc[tt] = (f32x4){0.f,0.f,0.f,0.f};

  const ushort* cbase = Cb + (size_t)(d0 + lr)*Ss + 8*lq;
  #pragma unroll
  for (int tt = 0; tt < 16; ++tt) {
    const ushort* cp = cbase + (size_t)tt*16*Ss;
    short8 b0 = *(const short8*)(cp);
    short8 b1 = *(const short8*)(cp + 32);
    acc[tt] = __builtin_amdgcn_mfma_f32_16x16x32_bf16(a0, b0, acc[tt], 0, 0, 0);
    acc[tt] = __builtin_amdgcn_mfma_f32_16x16x32_bf16(a1, b1, acc[tt], 0, 0, 0);
  }

  // GELU (inline exact erf) + per-row partials. acc[tt][j] at (row 4*lq+j, d d0+16*tt+lr)
  float ps[4] = {0,0,0,0}, pq[4] = {0,0,0,0};
  #pragma unroll
  for (int tt = 0; tt < 16; ++tt) {
    #pragma unroll
    for (int j = 0; j < 4; ++j) {
      float g = gelu_erf(acc[tt][j]);
      acc[tt][j] = g;
      ps[j] += g;
      pq[j] += g * g;
    }
  }
  // butterfly across the 16-lane group (sums over this wave's d-quadrant)
  #pragma unroll
  for (int off = 1; off < 16; off <<= 1) {
    #pragma unroll
    for (int j = 0; j < 4; ++j) {
      ps[j] += __shfl_xor(ps[j], off);
      pq[j] += __shfl_xor(pq[j], off);
    }
  }
  if (lr == 0) {
    #pragma unroll
    for (int j = 0; j < 4; ++j) {
      red[wv][lq][j][0] = ps[j];
      red[wv][lq][j][1] = pq[j];
    }
  }
  __syncthreads();
  if (t < 16) {
    const int g = t >> 2, j = t & 3;    // row t = 4g + j
    float sm = red[0][g][j][0] + red[1][g][j][0] + red[2][g][j][0] + red[3][g][j][0];
    float sq = red[0][g][j][1] + red[1][g][j][1] + red[2][g][j][1] + red[3][g][j][1];
    float mean = sm * (1.f/1024.f);
    float var  = sq * (1.f/1024.f) - mean*mean;
    mrs[t][0] = mean;
    mrs[t][1] = rsqrtf(var + 1e-5f);
  }
  __syncthreads();

  // Direct epilogue: normalize from registers, plain scalar stores.
  #pragma unroll
  for (int tt = 0; tt < 16; ++tt) {
    const int d = d0 + 16*tt + lr;
    const float gm = gamma[d], be = beta[d];
    #pragma unroll
    for (int j = 0; j < 4; ++j) {
      const int r = 4*lq + j;
      float o = (acc[tt][j] - mrs[r][0]) * mrs[r][1] * gm + be;
      out[(row0 + r)*Dd + d] = fixv(o);
    }
  }
}

extern "C" void kernel_launch(void* const* d_in, const int* in_sizes, int n_in,
                              void* d_out, int out_size, void* d_ws, size_t ws_size,
                              hipStream_t stream) {
  (void)in_sizes; (void)n_in; (void)out_size; (void)ws_size;
  const float* x     = (const float*)d_in[0];
  const float* A     = (const float*)d_in[1];
  const float* Bm    = (const float*)d_in[2];
  const float* C     = (const float*)d_in[3];
  const float* gamma = (const float*)d_in[4];
  const float* beta  = (const float*)d_in[5];
  float* out = (float*)d_out;

  // ws: uB f32 (4 MB) | states bf16 (2 MB) | C bf16 (128 KB) | Bm bf16 (128 KB)
  float*  uB  = (float*)d_ws;
  ushort* stb = (ushort*)(uB + (size_t)RTOT * Ss);
  ushort* Cb  = stb + (size_t)RTOT * Ss;
  ushort* Bmb = Cb + (size_t)Dd * Ss;

  k_prep <<<128, 256, 0, stream>>>(Bm, C, Bmb, Cb);
  k_gemm1<<<RTOT/32, 256, 0, stream>>>(x, Bmb, uB);
  k_scan <<<(Bsz*CHUNKS_PER_B)/4, 256, 0, stream>>>(uB, A, stb);
  k_out  <<<RTOT/16, 256, 0, stream>>>(stb, Cb, gamma, beta, out);
}

// Round 8
// 91.420 us; speedup vs baseline: 1.7396x; 1.0053x over previous
//
#include <hip/hip_runtime.h>
#include <hip/hip_bf16.h>
#include <math.h>

// Problem constants
#define Bsz  4
#define Lseq 4096
#define Dd   1024
#define Ss   64
#define RTOT (Bsz*Lseq)        // 16384 rows total

// Scan chunking: ||A||_op ~ 0.16 => ||A^12|| <= 3e-10, warm-up start exact to fp32
#define LC   16
#define WARM 12
#define CHUNKS_PER_B (Lseq/LC) // 256

typedef __attribute__((ext_vector_type(8))) short short8;
typedef __attribute__((ext_vector_type(4))) float f32x4;

__device__ __forceinline__ ushort f2bf(float f) {
  unsigned u = __float_as_uint(f);
  unsigned r = (u + 0x7FFFu + ((u >> 16) & 1u)) >> 16;   // RNE
  return (ushort)r;
}

// v_cvt_pk_bf16_f32 path (compiler-scheduled, RNE)
__device__ __forceinline__ unsigned cvtpk(float lo, float hi) {
  __hip_bfloat162 h = __float22bfloat162_rn(make_float2(lo, hi));
  union { __hip_bfloat162 h; unsigned u; } c; c.h = h;
  return c.u;
}

__device__ __forceinline__ short8 pack8v(f32x4 a, f32x4 b) {
  union { short8 s; unsigned u[4]; } r;
  r.u[0] = cvtpk(a[0], a[1]);
  r.u[1] = cvtpk(a[2], a[3]);
  r.u[2] = cvtpk(b[0], b[1]);
  r.u[3] = cvtpk(b[2], b[3]);
  return r.s;
}

// Inline exact-erf GELU (A&S 7.1.26, |eps|<=1.5e-7) — no call boundary.
__device__ __forceinline__ float gelu_erf(float v) {
  float x  = v * 0.70710678118654752f;
  float ax = fabsf(x);
  float t  = __builtin_amdgcn_rcpf(fmaf(0.3275911f, ax, 1.f));
  float p  = fmaf(1.061405429f, t, -1.453152027f);
  p = fmaf(p, t, 1.421413741f);
  p = fmaf(p, t, -0.284496736f);
  p = fmaf(p, t, 0.254829592f);
  p = p * t;
  float e  = __expf(-x * x);
  float er = fmaf(-p, e, 1.f);          // erf(|x|)
  er = copysignf(er, x);
  return 0.5f * v * (1.f + er);
}

// ---------------- prep: Bm, C -> bf16 ----------------
__global__ __launch_bounds__(256) void k_prep(const float* __restrict__ Bm,
                                              const float* __restrict__ C,
                                              ushort* __restrict__ Bmb,
                                              ushort* __restrict__ Cb) {
  int idx = blockIdx.x * 256 + threadIdx.x;   // float4 index, 32768 total
  const float* src; ushort* dst; int off;
  if (idx < 16384) { src = Bm; dst = Bmb; off = idx; }
  else             { src = C;  dst = Cb;  off = idx - 16384; }
  float4 v = *(const float4*)&src[(size_t)off*4];
  ushort4 o;
  o.x = f2bf(v.x); o.y = f2bf(v.y); o.z = f2bf(v.z); o.w = f2bf(v.w);
  *(ushort4*)&dst[(size_t)off*4] = o;
}

// ---------------- GEMM1 (MFMA, LDS-free): uB[r][n] = sum_k x[r][k]*Bm[n][k] ----
// Block 256 = 4 waves = 2m x 2n. Wave: 16 rows x 32 cols, K=1024.
__global__ __launch_bounds__(256) void k_gemm1(const float* __restrict__ x,
                                               const ushort* __restrict__ Bmb,
                                               float* __restrict__ uB) {
  const int l  = threadIdx.x & 63;
  const int wv = threadIdx.x >> 6;
  const int wm = wv >> 1, wn = wv & 1;
  const int row0 = blockIdx.x * 32 + wm * 16;
  const int n0   = wn * 32;
  const int lr = l & 15, lq = l >> 4;

  f32x4 acc0 = {0.f,0.f,0.f,0.f}, acc1 = {0.f,0.f,0.f,0.f};
  const f32x4*  xa  = (const f32x4*)(x + (size_t)(row0 + lr) * Dd + 8*lq);
  const ushort* bp0 = Bmb + (size_t)(n0      + lr) * Dd + 8*lq;
  const ushort* bp1 = Bmb + (size_t)(n0 + 16 + lr) * Dd + 8*lq;

  #pragma unroll 8
  for (int ks = 0; ks < 32; ++ks) {
    f32x4 alo = xa[8*ks];
    f32x4 ahi = xa[8*ks + 1];
    short8 b0 = *(const short8*)(bp0 + 32*ks);
    short8 b1 = *(const short8*)(bp1 + 32*ks);
    short8 a  = pack8v(alo, ahi);
    acc0 = __builtin_amdgcn_mfma_f32_16x16x32_bf16(a, b0, acc0, 0, 0, 0);
    acc1 = __builtin_amdgcn_mfma_f32_16x16x32_bf16(a, b1, acc1, 0, 0, 0);
  }
  const int orow = row0 + 4*lq;
  #pragma unroll
  for (int j = 0; j < 4; ++j) {
    uB[(size_t)(orow + j)*Ss + n0 + lr]      = acc0[j];
    uB[(size_t)(orow + j)*Ss + n0 + 16 + lr] = acc1[j];
  }
}

// ---------------- Scan: s_t = A s_{t-1} + u_t (chunked, warm-up), bf16 out ----
__device__ __forceinline__ float bcast_lane(float v, int l) {
  return __int_as_float(__builtin_amdgcn_readlane(__float_as_int(v), l));
}

__global__ __launch_bounds__(256) void k_scan(const float* __restrict__ uB,
                                              const float* __restrict__ A,
                                              ushort* __restrict__ stb) {
  const int lane  = threadIdx.x & 63;
  const int wv    = threadIdx.x >> 6;
  const int chunk = blockIdx.x * 4 + wv;        // 0..1023
  const int b     = chunk >> 8;
  const int c     = chunk & (CHUNKS_PER_B-1);

  float arow[64];
  #pragma unroll
  for (int i = 0; i < 64; i += 4) {
    float4 v = *(const float4*)&A[lane*64 + i];
    arow[i] = v.x; arow[i+1] = v.y; arow[i+2] = v.z; arow[i+3] = v.w;
  }

  const int cs = c * LC;
  const int t0 = (cs >= WARM) ? (cs - WARM) : 0;
  float s = 0.f;
  const float* up = uB  + ((size_t)b*Lseq + t0)*Ss + lane;
  ushort*      sp = stb + ((size_t)b*Lseq + cs)*Ss + lane;

  for (int tt = t0; tt < cs + LC; ++tt, up += Ss) {
    float u = *up;
    float a0 = u, a1 = 0.f, a2 = 0.f, a3 = 0.f;
    #pragma unroll
    for (int i = 0; i < 64; i += 4) {
      a0 += bcast_lane(s, i  ) * arow[i  ];
      a1 += bcast_lane(s, i+1) * arow[i+1];
      a2 += bcast_lane(s, i+2) * arow[i+2];
      a3 += bcast_lane(s, i+3) * arow[i+3];
    }
    s = (a0 + a1) + (a2 + a3);
    if (tt >= cs) { *sp = f2bf(s); sp += Ss; }
  }
}

// ---------------- Fused out (MFMA, OPERANDS SWAPPED): y^T layout ----
// D = Cb_frag x st_frag: D-row = d (4 consecutive per lane), D-col = r.
// Lane l, tile tt: d = d0 + 16*tt + 4*(l>>4) + j, r = l&15.
// -> epilogue is 16 float4 stores/thread, 64B-contiguous per row segment.
__device__ __forceinline__ float fixv(float v) {
  if (isnan(v)) return 0.f;
  if (isinf(v)) return v > 0.f ? 1000000.0f : -1000000.0f;
  return v;
}

__global__ __launch_bounds__(256) void k_out(const ushort* __restrict__ stb,
                                             const ushort* __restrict__ Cb,
                                             const float* __restrict__ gamma,
                                             const float* __restrict__ beta,
                                             float* __restrict__ out) {
  __shared__ float reds[4][16];
  __shared__ float redq[4][16];
  __shared__ float mrs[16][2];
  const int t  = threadIdx.x;
  const int l  = t & 63;
  const int wv = t >> 6;
  const int lr = l & 15, lq = l >> 4;
  const size_t row0 = (size_t)blockIdx.x * 16;

  // st B-frags direct from global (L2-hot; no LDS, no bank conflicts, no barrier)
  const ushort* sp = stb + (row0 + lr)*Ss + 8*lq;
  short8 s0 = *(const short8*)(sp);
  short8 s1 = *(const short8*)(sp + 32);

  const int d0 = wv * 256;
  f32x4 acc[16];
  #pragma unroll
  for (int tt = 0; tt < 16; ++tt) acc[tt] = (f32x4){0.f,0.f,0.f,0.f};

  const ushort* cbase = Cb + (size_t)(d0 + lr)*Ss + 8*lq;
  #pragma unroll
  for (int tt = 0; tt < 16; ++tt) {
    const ushort* cp = cbase + (size_t)tt*16*Ss;
    short8 c0 = *(const short8*)(cp);
    short8 c1 = *(const short8*)(cp + 32);
    acc[tt] = __builtin_amdgcn_mfma_f32_16x16x32_bf16(c0, s0, acc[tt], 0, 0, 0);
    acc[tt] = __builtin_amdgcn_mfma_f32_16x16x32_bf16(c1, s1, acc[tt], 0, 0, 0);
  }

  // GELU (inline exact erf) + per-row partials. Lane's row is fixed: r = lr.
  float ps = 0.f, pq = 0.f;
  #pragma unroll
  for (int tt = 0; tt < 16; ++tt) {
    #pragma unroll
    for (int j = 0; j < 4; ++j) {
      float g = gelu_erf(acc[tt][j]);
      acc[tt][j] = g;
      ps += g;
      pq += g * g;
    }
  }
  // sum over the 4 lq-groups holding the same row (lanes l, l^16, l^32, l^48)
  ps += __shfl_xor(ps, 16); ps += __shfl_xor(ps, 32);
  pq += __shfl_xor(pq, 16); pq += __shfl_xor(pq, 32);
  if (l < 16) { reds[wv][l] = ps; redq[wv][l] = pq; }
  __syncthreads();
  if (t < 16) {
    float sm = reds[0][t] + reds[1][t] + reds[2][t] + reds[3][t];
    float sq = redq[0][t] + redq[1][t] + redq[2][t] + redq[3][t];
    float mean = sm * (1.f/1024.f);
    float var  = sq * (1.f/1024.f) - mean*mean;   // biased, matches reference
    mrs[t][0] = mean;
    mrs[t][1] = rsqrtf(var + 1e-5f);
  }
  __syncthreads();

  const float mean = mrs[lr][0], rsig = mrs[lr][1];
  float* orow = out + (row0 + lr)*Dd;
  #pragma unroll
  for (int tt = 0; tt < 16; ++tt) {
    const int d = d0 + 16*tt + 4*lq;
    float4 g4 = *(const float4*)&gamma[d];
    float4 b4 = *(const float4*)&beta[d];
    f32x4 o;
    o[0] = fixv(fmaf((acc[tt][0] - mean) * rsig, g4.x, b4.x));
    o[1] = fixv(fmaf((acc[tt][1] - mean) * rsig, g4.y, b4.y));
    o[2] = fixv(fmaf((acc[tt][2] - mean) * rsig, g4.z, b4.z));
    o[3] = fixv(fmaf((acc[tt][3] - mean) * rsig, g4.w, b4.w));
    *(f32x4*)&orow[d] = o;
  }
}

extern "C" void kernel_launch(void* const* d_in, const int* in_sizes, int n_in,
                              void* d_out, int out_size, void* d_ws, size_t ws_size,
                              hipStream_t stream) {
  (void)in_sizes; (void)n_in; (void)out_size; (void)ws_size;
  const float* x     = (const float*)d_in[0];
  const float* A     = (const float*)d_in[1];
  const float* Bm    = (const float*)d_in[2];
  const float* C     = (const float*)d_in[3];
  const float* gamma = (const float*)d_in[4];
  const float* beta  = (const float*)d_in[5];
  float* out = (float*)d_out;

  // ws: uB f32 (4 MB) | states bf16 (2 MB) | C bf16 (128 KB) | Bm bf16 (128 KB)
  float*  uB  = (float*)d_ws;
  ushort* stb = (ushort*)(uB + (size_t)RTOT * Ss);
  ushort* Cb  = stb + (size_t)RTOT * Ss;
  ushort* Bmb = Cb + (size_t)Dd * Ss;

  k_prep <<<128, 256, 0, stream>>>(Bm, C, Bmb, Cb);
  k_gemm1<<<RTOT/32, 256, 0, stream>>>(x, Bmb, uB);
  k_scan <<<(Bsz*CHUNKS_PER_B)/4, 256, 0, stream>>>(uB, A, stb);
  k_out  <<<RTOT/16, 256, 0, stream>>>(stb, Cb, gamma, beta, out);
}

// Round 9
// 84.611 us; speedup vs baseline: 1.8796x; 1.0805x over previous
//
#include <hip/hip_runtime.h>
#include <hip/hip_bf16.h>
#include <math.h>

// Problem constants
#define Bsz  4
#define Lseq 4096
#define Dd   1024
#define Ss   64
#define RTOT (Bsz*Lseq)        // 16384 rows total

// Scan chunking: ||A||_op ~ 0.16 => ||A^12|| <= 3e-10, warm-up start exact to fp32
#define LC   16
#define WARM 12
#define CHUNKS_PER_B (Lseq/LC) // 256

typedef __attribute__((ext_vector_type(8))) short short8;
typedef __attribute__((ext_vector_type(4))) float f32x4;

__device__ __forceinline__ ushort f2bf(float f) {
  unsigned u = __float_as_uint(f);
  unsigned r = (u + 0x7FFFu + ((u >> 16) & 1u)) >> 16;   // RNE
  return (ushort)r;
}

// v_cvt_pk_bf16_f32 path (compiler-scheduled, RNE)
__device__ __forceinline__ unsigned cvtpk(float lo, float hi) {
  __hip_bfloat162 h = __float22bfloat162_rn(make_float2(lo, hi));
  union { __hip_bfloat162 h; unsigned u; } c; c.h = h;
  return c.u;
}

__device__ __forceinline__ short8 pack8v(f32x4 a, f32x4 b) {
  union { short8 s; unsigned u[4]; } r;
  r.u[0] = cvtpk(a[0], a[1]);
  r.u[1] = cvtpk(a[2], a[3]);
  r.u[2] = cvtpk(b[0], b[1]);
  r.u[3] = cvtpk(b[2], b[3]);
  return r.s;
}

// Inline exact-erf GELU (A&S 7.1.26, |eps|<=1.5e-7) — no call boundary.
__device__ __forceinline__ float gelu_erf(float v) {
  float x  = v * 0.70710678118654752f;
  float ax = fabsf(x);
  float t  = __builtin_amdgcn_rcpf(fmaf(0.3275911f, ax, 1.f));
  float p  = fmaf(1.061405429f, t, -1.453152027f);
  p = fmaf(p, t, 1.421413741f);
  p = fmaf(p, t, -0.284496736f);
  p = fmaf(p, t, 0.254829592f);
  p = p * t;
  float e  = __expf(-x * x);
  float er = fmaf(-p, e, 1.f);          // erf(|x|)
  er = copysignf(er, x);
  return 0.5f * v * (1.f + er);
}

// ---------------- prep: Bm, C -> bf16 ----------------
__global__ __launch_bounds__(256) void k_prep(const float* __restrict__ Bm,
                                              const float* __restrict__ C,
                                              ushort* __restrict__ Bmb,
                                              ushort* __restrict__ Cb) {
  int idx = blockIdx.x * 256 + threadIdx.x;   // float4 index, 32768 total
  const float* src; ushort* dst; int off;
  if (idx < 16384) { src = Bm; dst = Bmb; off = idx; }
  else             { src = C;  dst = Cb;  off = idx - 16384; }
  float4 v = *(const float4*)&src[(size_t)off*4];
  ushort4 o;
  o.x = f2bf(v.x); o.y = f2bf(v.y); o.z = f2bf(v.z); o.w = f2bf(v.w);
  *(ushort4*)&dst[(size_t)off*4] = o;
}

// ---------------- GEMM1 (MFMA, LDS-free): uB[r][n] = sum_k x[r][k]*Bm[n][k] ----
// Block 256 = 4 waves = 2m x 2n. Wave: 16 rows x 32 cols, K=1024.
// unroll 16 + 170-VGPR cap: deeper load-ahead on the 16-row x-gather.
__global__ __launch_bounds__(256, 3) void k_gemm1(const float* __restrict__ x,
                                                  const ushort* __restrict__ Bmb,
                                                  float* __restrict__ uB) {
  const int l  = threadIdx.x & 63;
  const int wv = threadIdx.x >> 6;
  const int wm = wv >> 1, wn = wv & 1;
  const int row0 = blockIdx.x * 32 + wm * 16;
  const int n0   = wn * 32;
  const int lr = l & 15, lq = l >> 4;

  f32x4 acc0 = {0.f,0.f,0.f,0.f}, acc1 = {0.f,0.f,0.f,0.f};
  const f32x4*  xa  = (const f32x4*)(x + (size_t)(row0 + lr) * Dd + 8*lq);
  const ushort* bp0 = Bmb + (size_t)(n0      + lr) * Dd + 8*lq;
  const ushort* bp1 = Bmb + (size_t)(n0 + 16 + lr) * Dd + 8*lq;

  #pragma unroll 16
  for (int ks = 0; ks < 32; ++ks) {
    f32x4 alo = xa[8*ks];
    f32x4 ahi = xa[8*ks + 1];
    short8 b0 = *(const short8*)(bp0 + 32*ks);
    short8 b1 = *(const short8*)(bp1 + 32*ks);
    short8 a  = pack8v(alo, ahi);
    acc0 = __builtin_amdgcn_mfma_f32_16x16x32_bf16(a, b0, acc0, 0, 0, 0);
    acc1 = __builtin_amdgcn_mfma_f32_16x16x32_bf16(a, b1, acc1, 0, 0, 0);
  }
  const int orow = row0 + 4*lq;
  #pragma unroll
  for (int j = 0; j < 4; ++j) {
    uB[(size_t)(orow + j)*Ss + n0 + lr]      = acc0[j];
    uB[(size_t)(orow + j)*Ss + n0 + 16 + lr] = acc1[j];
  }
}

// ---------------- Scan: s_t = A s_{t-1} + u_t (chunked, warm-up), bf16 out ----
__device__ __forceinline__ float bcast_lane(float v, int l) {
  return __int_as_float(__builtin_amdgcn_readlane(__float_as_int(v), l));
}

__global__ __launch_bounds__(256) void k_scan(const float* __restrict__ uB,
                                              const float* __restrict__ A,
                                              ushort* __restrict__ stb) {
  const int lane  = threadIdx.x & 63;
  const int wv    = threadIdx.x >> 6;
  const int chunk = blockIdx.x * 4 + wv;        // 0..1023
  const int b     = chunk >> 8;
  const int c     = chunk & (CHUNKS_PER_B-1);

  float arow[64];
  #pragma unroll
  for (int i = 0; i < 64; i += 4) {
    float4 v = *(const float4*)&A[lane*64 + i];
    arow[i] = v.x; arow[i+1] = v.y; arow[i+2] = v.z; arow[i+3] = v.w;
  }

  const int cs = c * LC;
  const int t0 = (cs >= WARM) ? (cs - WARM) : 0;
  float s = 0.f;
  const float* up = uB  + ((size_t)b*Lseq + t0)*Ss + lane;
  ushort*      sp = stb + ((size_t)b*Lseq + cs)*Ss + lane;

  for (int tt = t0; tt < cs + LC; ++tt, up += Ss) {
    float u = *up;
    float a0 = u, a1 = 0.f, a2 = 0.f, a3 = 0.f;
    #pragma unroll
    for (int i = 0; i < 64; i += 4) {
      a0 += bcast_lane(s, i  ) * arow[i  ];
      a1 += bcast_lane(s, i+1) * arow[i+1];
      a2 += bcast_lane(s, i+2) * arow[i+2];
      a3 += bcast_lane(s, i+3) * arow[i+3];
    }
    s = (a0 + a1) + (a2 + a3);
    if (tt >= cs) { *sp = f2bf(s); sp += Ss; }
  }
}

// ---------------- Fused out (MFMA, swapped operands, 2 row-groups/wave) ----
// D = Cb_frag x st_frag: lane l, tile tt: d = d0+16tt+4*(l>>4)+j, r = l&15.
// 2 row-groups per wave: each C-frag pair feeds 4 MFMAs (2x arithmetic
// intensity per L2 gather); launch_bounds(256,2) gives VGPR headroom for MLP.
__device__ __forceinline__ float fixv(float v) {
  if (isnan(v)) return 0.f;
  if (isinf(v)) return v > 0.f ? 1000000.0f : -1000000.0f;
  return v;
}

__global__ __launch_bounds__(256, 2) void k_out(const ushort* __restrict__ stb,
                                                const ushort* __restrict__ Cb,
                                                const float* __restrict__ gamma,
                                                const float* __restrict__ beta,
                                                float* __restrict__ out) {
  __shared__ float reds[4][2][16];
  __shared__ float redq[4][2][16];
  __shared__ float mrs[32][2];
  const int t  = threadIdx.x;
  const int l  = t & 63;
  const int wv = t >> 6;
  const int lr = l & 15, lq = l >> 4;
  const size_t row0 = (size_t)blockIdx.x * 32;

  // st B-frags for the 2 row-groups (L2-hot, no LDS)
  const ushort* sp0 = stb + (row0      + lr)*Ss + 8*lq;
  const ushort* sp1 = stb + (row0 + 16 + lr)*Ss + 8*lq;
  short8 sA0 = *(const short8*)(sp0);
  short8 sA1 = *(const short8*)(sp0 + 32);
  short8 sB0 = *(const short8*)(sp1);
  short8 sB1 = *(const short8*)(sp1 + 32);

  const int d0 = wv * 256;
  f32x4 accA[16], accB[16];
  #pragma unroll
  for (int tt = 0; tt < 16; ++tt) {
    accA[tt] = (f32x4){0.f,0.f,0.f,0.f};
    accB[tt] = (f32x4){0.f,0.f,0.f,0.f};
  }

  const ushort* cbase = Cb + (size_t)(d0 + lr)*Ss + 8*lq;
  #pragma unroll
  for (int tt = 0; tt < 16; ++tt) {
    const ushort* cp = cbase + (size_t)tt*16*Ss;
    short8 c0 = *(const short8*)(cp);
    short8 c1 = *(const short8*)(cp + 32);
    accA[tt] = __builtin_amdgcn_mfma_f32_16x16x32_bf16(c0, sA0, accA[tt], 0, 0, 0);
    accA[tt] = __builtin_amdgcn_mfma_f32_16x16x32_bf16(c1, sA1, accA[tt], 0, 0, 0);
    accB[tt] = __builtin_amdgcn_mfma_f32_16x16x32_bf16(c0, sB0, accB[tt], 0, 0, 0);
    accB[tt] = __builtin_amdgcn_mfma_f32_16x16x32_bf16(c1, sB1, accB[tt], 0, 0, 0);
  }

  // GELU + per-row partials; lane's row is r = lr within each group.
  float psA = 0.f, pqA = 0.f, psB = 0.f, pqB = 0.f;
  #pragma unroll
  for (int tt = 0; tt < 16; ++tt) {
    #pragma unroll
    for (int j = 0; j < 4; ++j) {
      float gA = gelu_erf(accA[tt][j]);
      accA[tt][j] = gA; psA += gA; pqA += gA * gA;
      float gB = gelu_erf(accB[tt][j]);
      accB[tt][j] = gB; psB += gB; pqB += gB * gB;
    }
  }
  psA += __shfl_xor(psA, 16); psA += __shfl_xor(psA, 32);
  pqA += __shfl_xor(pqA, 16); pqA += __shfl_xor(pqA, 32);
  psB += __shfl_xor(psB, 16); psB += __shfl_xor(psB, 32);
  pqB += __shfl_xor(pqB, 16); pqB += __shfl_xor(pqB, 32);
  if (l < 16) {
    reds[wv][0][l] = psA; redq[wv][0][l] = pqA;
    reds[wv][1][l] = psB; redq[wv][1][l] = pqB;
  }
  __syncthreads();
  if (t < 32) {
    const int rg = t >> 4, r = t & 15;
    float sm = reds[0][rg][r] + reds[1][rg][r] + reds[2][rg][r] + reds[3][rg][r];
    float sq = redq[0][rg][r] + redq[1][rg][r] + redq[2][rg][r] + redq[3][rg][r];
    float mean = sm * (1.f/1024.f);
    float var  = sq * (1.f/1024.f) - mean*mean;   // biased, matches reference
    mrs[t][0] = mean;
    mrs[t][1] = rsqrtf(var + 1e-5f);
  }
  __syncthreads();

  const float meanA = mrs[lr][0],      rsigA = mrs[lr][1];
  const float meanB = mrs[16 + lr][0], rsigB = mrs[16 + lr][1];
  float* orowA = out + (row0      + lr)*Dd;
  float* orowB = out + (row0 + 16 + lr)*Dd;
  #pragma unroll
  for (int tt = 0; tt < 16; ++tt) {
    const int d = d0 + 16*tt + 4*lq;
    float4 g4 = *(const float4*)&gamma[d];
    float4 b4 = *(const float4*)&beta[d];
    f32x4 oA, oB;
    #pragma unroll
    for (int j = 0; j < 4; ++j) {
      float gj = (&g4.x)[j], bj = (&b4.x)[j];
      oA[j] = fixv(fmaf((accA[tt][j] - meanA) * rsigA, gj, bj));
      oB[j] = fixv(fmaf((accB[tt][j] - meanB) * rsigB, gj, bj));
    }
    *(f32x4*)&orowA[d] = oA;
    *(f32x4*)&orowB[d] = oB;
  }
}

extern "C" void kernel_launch(void* const* d_in, const int* in_sizes, int n_in,
                              void* d_out, int out_size, void* d_ws, size_t ws_size,
                              hipStream_t stream) {
  (void)in_sizes; (void)n_in; (void)out_size; (void)ws_size;
  const float* x     = (const float*)d_in[0];
  const float* A     = (const float*)d_in[1];
  const float* Bm    = (const float*)d_in[2];
  const float* C     = (const float*)d_in[3];
  const float* gamma = (const float*)d_in[4];
  const float* beta  = (const float*)d_in[5];
  float* out = (float*)d_out;

  // ws: uB f32 (4 MB) | states bf16 (2 MB) | C bf16 (128 KB) | Bm bf16 (128 KB)
  float*  uB  = (float*)d_ws;
  ushort* stb = (ushort*)(uB + (size_t)RTOT * Ss);
  ushort* Cb  = stb + (size_t)RTOT * Ss;
  ushort* Bmb = Cb + (size_t)Dd * Ss;

  k_prep <<<128, 256, 0, stream>>>(Bm, C, Bmb, Cb);
  k_gemm1<<<RTOT/32, 256, 0, stream>>>(x, Bmb, uB);
  k_scan <<<(Bsz*CHUNKS_PER_B)/4, 256, 0, stream>>>(uB, A, stb);
  k_out  <<<RTOT/32, 256, 0, stream>>>(stb, Cb, gamma, beta, out);
}